// Round 8
// baseline (391.486 us; speedup 1.0000x reference)
//
#include <hip/hip_runtime.h>
#include <hip/hip_bf16.h>

typedef short s8v  __attribute__((ext_vector_type(8)));
typedef float f4v  __attribute__((ext_vector_type(4)));
typedef unsigned short us8 __attribute__((ext_vector_type(8)));

__device__ __forceinline__ unsigned short f2bf(float x) {   // RTN-even
    unsigned u = __float_as_uint(x);
    unsigned r = ((u >> 16) & 1u) + 0x7FFFu;
    return (unsigned short)((u + r) >> 16);
}
__device__ __forceinline__ float bf2f(unsigned short h) {
    return __uint_as_float(((unsigned)h) << 16);
}

// ---------------- X0 = ent_tab[entity] (fp32 + bf16 mirror) ----------------
__global__ __launch_bounds__(256) void x0_kernel(
    const float* __restrict__ tab, const int* __restrict__ entity,
    float* __restrict__ X0, unsigned short* __restrict__ X0b, int N)
{
    int idx = blockIdx.x * 256 + threadIdx.x;
    int n = idx >> 5, l = idx & 31;
    if (n < N) {
        int src = entity[n];
        float4 v = *(const float4*)&tab[(size_t)src * 128 + l * 4];
        *(float4*)&X0[(size_t)n * 128 + l * 4] = v;
        ushort4 b;
        b.x = f2bf(v.x); b.y = f2bf(v.y); b.z = f2bf(v.z); b.w = f2bf(v.w);
        *(ushort4*)&X0b[(size_t)n * 128 + l * 4] = b;
    }
}

// ---------------- B prep: Bt[n][k] hi/lo bf16 for both layers ----------------
__global__ __launch_bounds__(256) void bprep_kernel(
    const float* __restrict__ basis1, const float* __restrict__ root1,
    const float* __restrict__ basis2, const float* __restrict__ root2,
    unsigned short* __restrict__ Bt1h, unsigned short* __restrict__ Bt1l,
    unsigned short* __restrict__ Bt2h, unsigned short* __restrict__ Bt2l)
{
    int idx = blockIdx.x * 256 + threadIdx.x;    // 0..81919
    int layer = blockIdx.y;
    int n = idx & 127, k = idx >> 7;             // k 0..639
    const float* basis = layer ? basis2 : basis1;
    const float* root  = layer ? root2  : root1;
    float v = (k < 512) ? basis[((k & 3) << 14) + ((k >> 2) << 7) + n]
                        : root[((k - 512) << 7) + n];
    unsigned short h = f2bf(v);
    unsigned short l = f2bf(v - bf2f(h));
    unsigned short* Bh = layer ? Bt2h : Bt1h;
    unsigned short* Bl = layer ? Bt2l : Bt1l;
    Bh[(size_t)n * 640 + k] = h;
    Bl[(size_t)n * 640 + k] = l;
}

// ---------------- CSR build ----------------
__global__ __launch_bounds__(256) void hist_kernel(
    const int* __restrict__ edge_index, int* __restrict__ deg, int E)
{
    int e = blockIdx.x * 256 + threadIdx.x;
    if (e < E) atomicAdd(&deg[edge_index[E + e]], 1);
}

__global__ __launch_bounds__(1024) void scanA_kernel(
    const int* __restrict__ deg, int* __restrict__ row_start,
    int* __restrict__ btot, int N)
{
    __shared__ int wtot[16];
    __shared__ int woff[16];
    const int tid = threadIdx.x, lane = tid & 63, wid = tid >> 6;
    int i = blockIdx.x * 1024 + tid;
    int v = (i < N) ? deg[i] : 0;
    int x = v;
    #pragma unroll
    for (int d = 1; d < 64; d <<= 1) {
        int t = __shfl_up(x, d, 64);
        if (lane >= d) x += t;
    }
    if (lane == 63) wtot[wid] = x;
    __syncthreads();
    if (wid == 0 && lane < 16) {
        int s = wtot[lane];
        int y = s;
        #pragma unroll
        for (int d = 1; d < 16; d <<= 1) {
            int t = __shfl_up(y, d, 16);
            if (lane >= d) y += t;
        }
        woff[lane] = y - s;
        if (lane == 15) btot[blockIdx.x] = y;
    }
    __syncthreads();
    if (i < N) row_start[i] = woff[wid] + (x - v);
}

__global__ __launch_bounds__(64) void scanB_kernel(
    const int* __restrict__ btot, int* __restrict__ boff,
    int* __restrict__ row_start, int nB, int N)
{
    int t = threadIdx.x;
    int v = (t < nB) ? btot[t] : 0;
    int x = v;
    #pragma unroll
    for (int d = 1; d < 64; d <<= 1) {
        int u = __shfl_up(x, d, 64);
        if (t >= d) x += u;
    }
    if (t < nB) boff[t] = x - v;
    if (t == nB - 1) row_start[N] = x;
}

__global__ __launch_bounds__(1024) void scanC_kernel(
    int* __restrict__ row_start, int* __restrict__ cursor,
    const int* __restrict__ boff, int N)
{
    int i = blockIdx.x * 1024 + threadIdx.x;
    if (i < N) {
        int r = row_start[i] + boff[blockIdx.x];
        row_start[i] = r;
        cursor[i]    = r;
    }
}

__global__ __launch_bounds__(256) void fill_kernel(
    const int* __restrict__ edge_index, const int* __restrict__ edge_type,
    const float* __restrict__ edge_norm, int* __restrict__ cursor,
    int* __restrict__ src_s, int* __restrict__ et_s, float* __restrict__ norm_s, int E)
{
    int e = blockIdx.x * 256 + threadIdx.x;
    if (e >= E) return;
    int dst = edge_index[E + e];
    int pos = atomicAdd(&cursor[dst], 1);
    src_s[pos]  = edge_index[e];
    et_s[pos]   = edge_type[e];
    norm_s[pos] = edge_norm[e];
}

// ---------------- edge agg (bf16 gather) -> w bf16 [N,512], k = 4d+b ----------------
__global__ __launch_bounds__(256) void edge_agg_kernel(
    const unsigned short* __restrict__ Xb,   // [N,128] bf16 mirror of layer input
    const int* __restrict__ row_start,
    const int* __restrict__ src_s, const int* __restrict__ et_s,
    const float* __restrict__ norm_s,
    const float* __restrict__ att,           // [R,4]
    unsigned short* __restrict__ w, int N)
{
    int n = blockIdx.x * 8 + (threadIdx.x >> 5);
    if (n >= N) return;
    int l = threadIdx.x & 31;                // dims 4l..4l+3
    int s0 = row_start[n], s1 = row_start[n + 1];
    float acc[4][4];
    #pragma unroll
    for (int d = 0; d < 4; ++d)
        #pragma unroll
        for (int b = 0; b < 4; ++b) acc[d][b] = 0.f;
    for (int p = s0; p < s1; ++p) {
        int   src  = src_s[p];
        int   et   = et_s[p];
        float norm = norm_s[p];
        float4 a = *(const float4*)(att + (size_t)et * 4);
        a.x *= norm; a.y *= norm; a.z *= norm; a.w *= norm;
        ushort4 xr = *(const ushort4*)&Xb[(size_t)src * 128 + (l << 2)];
        float xs[4] = {bf2f(xr.x), bf2f(xr.y), bf2f(xr.z), bf2f(xr.w)};
        #pragma unroll
        for (int d = 0; d < 4; ++d) {
            acc[d][0] = fmaf(a.x, xs[d], acc[d][0]);
            acc[d][1] = fmaf(a.y, xs[d], acc[d][1]);
            acc[d][2] = fmaf(a.z, xs[d], acc[d][2]);
            acc[d][3] = fmaf(a.w, xs[d], acc[d][3]);
        }
    }
    float inv = 1.0f / fmaxf((float)(s1 - s0), 1.0f);
    #pragma unroll
    for (int d = 0; d < 4; ++d) {
        ushort4 h;
        h.x = f2bf(acc[d][0] * inv);
        h.y = f2bf(acc[d][1] * inv);
        h.z = f2bf(acc[d][2] * inv);
        h.w = f2bf(acc[d][3] * inv);
        *(ushort4*)&w[(size_t)n * 512 + (l << 4) + (d << 2)] = h;
    }
}

// ---------------- GEMM K=640, split-bf16 MFMA, register-prefetch pipeline ----
// 32 rows/block, 256 threads (4 waves): wave = (row-half, col-half).
// A = [w(bf16, k<512) | X(fp32 split, k>=512)], B = Bt^T pre-split hi/lo.
__global__ __launch_bounds__(256) void gemm640_kernel(
    const unsigned short* __restrict__ wbf,   // [N,512] bf16
    const float* __restrict__ X,              // [N,128] fp32
    const unsigned short* __restrict__ Bth,   // [128][640]
    const unsigned short* __restrict__ Btl,
    const float* __restrict__ bias,
    float* __restrict__ Xout,
    unsigned short* __restrict__ Xoutb, int N)
{
    __shared__ unsigned short A_hi[32 * 40];
    __shared__ unsigned short A_lo[32 * 40];
    __shared__ unsigned short B_hi[128 * 40];
    __shared__ unsigned short B_lo[128 * 40];

    const int tid   = threadIdx.x;
    const int row0  = blockIdx.x * 32;
    const int lane  = tid & 63, wv = tid >> 6;
    const int ml    = lane & 15, quad = lane >> 4;
    const int rtile = (wv & 1) << 4;          // 0 / 16
    const int cgrp  = (wv >> 1) << 6;         // 0 / 64

    const int ar  = tid >> 2;                 // A stage row (tid<128)
    const int akv = (tid & 3) << 3;
    const int bn0 = tid >> 2,         bkv0 = (tid & 3) << 3;
    const int bn1 = (tid + 256) >> 2, bkv1 = ((tid + 256) & 3) << 3;

    const us8 z8 = {0, 0, 0, 0, 0, 0, 0, 0};
    us8 Ah = z8, Al = z8, Bh0, Bl0, Bh1, Bl1;

    auto loadA = [&](int k0) {
        if (tid < 128) {
            int gr = row0 + ar;
            if (k0 < 512) {
                Ah = (gr < N) ? *(const us8*)&wbf[(size_t)gr * 512 + k0 + akv] : z8;
            } else {
                float4 v0 = make_float4(0.f, 0.f, 0.f, 0.f), v1 = v0;
                if (gr < N) {
                    v0 = *(const float4*)&X[(size_t)gr * 128 + (k0 - 512) + akv];
                    v1 = *(const float4*)&X[(size_t)gr * 128 + (k0 - 512) + akv + 4];
                }
                float f[8] = {v0.x, v0.y, v0.z, v0.w, v1.x, v1.y, v1.z, v1.w};
                #pragma unroll
                for (int j = 0; j < 8; ++j) {
                    unsigned short h = f2bf(f[j]);
                    Ah[j] = (short)h;
                    Al[j] = (short)f2bf(f[j] - bf2f(h));
                }
            }
        }
    };
    auto loadB = [&](int k0) {
        Bh0 = *(const us8*)&Bth[(size_t)bn0 * 640 + k0 + bkv0];
        Bl0 = *(const us8*)&Btl[(size_t)bn0 * 640 + k0 + bkv0];
        Bh1 = *(const us8*)&Bth[(size_t)bn1 * 640 + k0 + bkv1];
        Bl1 = *(const us8*)&Btl[(size_t)bn1 * 640 + k0 + bkv1];
    };

    f4v acc[4];
    #pragma unroll
    for (int t = 0; t < 4; ++t) acc[t] = (f4v){0.f, 0.f, 0.f, 0.f};

    loadA(0); loadB(0);

    for (int kc = 0; kc < 20; ++kc) {
        const int k0 = kc * 32;
        if (kc) __syncthreads();              // LDS from prev chunk fully consumed

        if (tid < 128) {
            *(us8*)&A_hi[ar * 40 + akv] = Ah;
            if (k0 >= 512) *(us8*)&A_lo[ar * 40 + akv] = Al;
        }
        *(us8*)&B_hi[bn0 * 40 + bkv0] = Bh0;
        *(us8*)&B_lo[bn0 * 40 + bkv0] = Bl0;
        *(us8*)&B_hi[bn1 * 40 + bkv1] = Bh1;
        *(us8*)&B_lo[bn1 * 40 + bkv1] = Bl1;
        __syncthreads();

        if (kc < 19) { loadA(k0 + 32); loadB(k0 + 32); }   // overlap with MFMA

        s8v aH = *(const s8v*)&A_hi[(rtile + ml) * 40 + quad * 8];
        if (k0 < 512) {
            #pragma unroll
            for (int t = 0; t < 4; ++t) {
                int n = cgrp + t * 16 + ml;
                s8v bH = *(const s8v*)&B_hi[n * 40 + quad * 8];
                s8v bL = *(const s8v*)&B_lo[n * 40 + quad * 8];
                acc[t] = __builtin_amdgcn_mfma_f32_16x16x32_bf16(aH, bL, acc[t], 0, 0, 0);
                acc[t] = __builtin_amdgcn_mfma_f32_16x16x32_bf16(aH, bH, acc[t], 0, 0, 0);
            }
        } else {
            s8v aL = *(const s8v*)&A_lo[(rtile + ml) * 40 + quad * 8];
            #pragma unroll
            for (int t = 0; t < 4; ++t) {
                int n = cgrp + t * 16 + ml;
                s8v bH = *(const s8v*)&B_hi[n * 40 + quad * 8];
                s8v bL = *(const s8v*)&B_lo[n * 40 + quad * 8];
                acc[t] = __builtin_amdgcn_mfma_f32_16x16x32_bf16(aL, bH, acc[t], 0, 0, 0);
                acc[t] = __builtin_amdgcn_mfma_f32_16x16x32_bf16(aH, bL, acc[t], 0, 0, 0);
                acc[t] = __builtin_amdgcn_mfma_f32_16x16x32_bf16(aH, bH, acc[t], 0, 0, 0);
            }
        }
    }

    // epilogue: C/D layout col=lane&15, row=quad*4+reg
    #pragma unroll
    for (int t = 0; t < 4; ++t) {
        int gc = cgrp + t * 16 + ml;
        float bv = bias[gc];
        #pragma unroll
        for (int j = 0; j < 4; ++j) {
            int gr = row0 + rtile + quad * 4 + j;
            if (gr < N) {
                float v = fmaxf(acc[t][j] + bv, 0.f);
                Xout [(size_t)gr * 128 + gc] = v;
                Xoutb[(size_t)gr * 128 + gc] = f2bf(v);
            }
        }
    }
}

// ---------------- relation context: R2 = relu(DAD @ tab @ W) ----------------
__global__ __launch_bounds__(512) void relctx_kernel(
    const float* __restrict__ DAD,
    const float* __restrict__ tab,
    const float* __restrict__ W,
    float* __restrict__ R2, int NR)
{
    __shared__ float part[4][128];
    __shared__ float r1s[128];
    int r = blockIdx.x;
    int t = threadIdx.x;
    int o = t & 127, q = t >> 7;
    float s = 0.f;
    #pragma unroll 4
    for (int j = q; j < NR; j += 4)
        s = fmaf(DAD[r * NR + j], tab[j * 128 + o], s);
    part[q][o] = s;
    __syncthreads();
    if (t < 128) r1s[t] = part[0][t] + part[1][t] + part[2][t] + part[3][t];
    __syncthreads();
    float s2 = 0.f;
    #pragma unroll 8
    for (int k = q * 32; k < q * 32 + 32; ++k)
        s2 = fmaf(r1s[k], W[k * 128 + o], s2);
    part[q][o] = s2;
    __syncthreads();
    if (t < 128)
        R2[r * 128 + t] = fmaxf(part[0][t] + part[1][t] + part[2][t] + part[3][t], 0.f);
}

// ---------------- gated output ----------------
__global__ __launch_bounds__(256) void output_kernel(
    const int* __restrict__ samples,
    const float* __restrict__ gate_e,
    const float* __restrict__ gate_r,
    const float* __restrict__ ent_emb,
    const float* __restrict__ rel_emb,
    const float* __restrict__ ctx2,
    const float* __restrict__ relctx,
    float* __restrict__ out, int S)
{
    int s = blockIdx.x * 2 + (threadIdx.x >> 7);
    if (s >= S) return;
    int p = blockIdx.y;
    int o = threadIdx.x & 127;
    float v;
    if (p == 1) {
        int idx = samples[s * 3 + 1];
        float g = 1.0f / (1.0f + __expf(-gate_r[o]));
        v = g * rel_emb[idx * 128 + o] + (1.0f - g) * relctx[idx * 128 + o];
    } else {
        int idx = samples[s * 3 + (p == 0 ? 0 : 2)];
        float g = 1.0f / (1.0f + __expf(-gate_e[o]));
        v = g * ent_emb[(size_t)idx * 128 + o] + (1.0f - g) * ctx2[(size_t)idx * 128 + o];
    }
    out[(size_t)p * S * 128 + (size_t)s * 128 + o] = v;
}

extern "C" void kernel_launch(void* const* d_in, const int* in_sizes, int n_in,
                              void* d_out, int out_size, void* d_ws, size_t ws_size,
                              hipStream_t stream)
{
    const int*   entity     = (const int*)d_in[0];
    const int*   edge_index = (const int*)d_in[1];
    const int*   edge_type  = (const int*)d_in[2];
    const float* edge_norm  = (const float*)d_in[3];
    const int*   samples    = (const int*)d_in[4];
    const float* DAD        = (const float*)d_in[5];
    const float* ent_emb    = (const float*)d_in[6];
    const float* rel_emb    = (const float*)d_in[7];
    const float* ent_tab    = (const float*)d_in[8];
    const float* rel_tab    = (const float*)d_in[9];
    const float* Wrel       = (const float*)d_in[10];
    const float* gate_e     = (const float*)d_in[11];
    const float* gate_r     = (const float*)d_in[12];
    const float* basis1     = (const float*)d_in[13];
    const float* att1       = (const float*)d_in[14];
    const float* root1      = (const float*)d_in[15];
    const float* bias1      = (const float*)d_in[16];
    const float* basis2     = (const float*)d_in[17];
    const float* att2       = (const float*)d_in[18];
    const float* root2      = (const float*)d_in[19];
    const float* bias2      = (const float*)d_in[20];

    const int N  = in_sizes[0];        // 50000
    const int E  = in_sizes[2];        // 200000
    const int S  = in_sizes[4] / 3;    // 20000
    const int NR = in_sizes[9] / 128;  // 200

    float* ws      = (float*)d_ws;
    float* X0      = ws;                               // [N,128] f32
    float* X1      = X0 + (size_t)N * 128;             // [N,128] f32
    unsigned short* X0b = (unsigned short*)(X1 + (size_t)N * 128); // [N,128] bf16
    unsigned short* X1b = X0b + (size_t)N * 128;       // [N,128] bf16
    unsigned short* wbf = X1b + (size_t)N * 128;       // [N,512] bf16
    float* Rc      = (float*)(wbf + (size_t)N * 512);  // [NR,128] f32
    int*   deg     = (int*)(Rc + (size_t)NR * 128);    // [N]
    int*   rstart  = deg + N;                          // [N+1]
    int*   cursor  = rstart + N + 1;                   // [N]
    int*   src_s   = cursor + N;                       // [E]
    int*   et_s    = src_s + E;                        // [E]
    float* norm_s  = (float*)(et_s + E);               // [E]
    int*   btot    = (int*)(norm_s + E);               // [64]
    int*   boff    = btot + 64;                        // [64]
    uintptr_t bt   = ((uintptr_t)(boff + 64) + 15) & ~(uintptr_t)15;
    unsigned short* Bt1h = (unsigned short*)bt;        // [128*640] each
    unsigned short* Bt1l = Bt1h + 128 * 640;
    unsigned short* Bt2h = Bt1l + 128 * 640;
    unsigned short* Bt2l = Bt2h + 128 * 640;

    const int egrid = (E + 255) / 256;
    const int ggrid = (N + 31) / 32;
    const int agrid = (N + 7) / 8;
    const int nB    = (N + 1023) / 1024;

    // ---- weight prep + CSR build ----
    bprep_kernel<<<dim3(320, 2), 256, 0, stream>>>(basis1, root1, basis2, root2,
                                                   Bt1h, Bt1l, Bt2h, Bt2l);
    hipMemsetAsync(deg, 0, (size_t)N * sizeof(int), stream);
    hist_kernel<<<egrid, 256, 0, stream>>>(edge_index, deg, E);
    scanA_kernel<<<nB, 1024, 0, stream>>>(deg, rstart, btot, N);
    scanB_kernel<<<1, 64, 0, stream>>>(btot, boff, rstart, nB, N);
    scanC_kernel<<<nB, 1024, 0, stream>>>(rstart, cursor, boff, N);
    fill_kernel<<<egrid, 256, 0, stream>>>(edge_index, edge_type, edge_norm, cursor,
                                           src_s, et_s, norm_s, E);

    // ---- X0 = ent_tab[entity] ----
    x0_kernel<<<(N * 32 + 255) / 256, 256, 0, stream>>>(ent_tab, entity, X0, X0b, N);

    // ---- layer 1: X1 = relu([agg(X0)|X0] @ W1) ----
    edge_agg_kernel<<<agrid, 256, 0, stream>>>(X0b, rstart, src_s, et_s, norm_s, att1, wbf, N);
    gemm640_kernel<<<ggrid, 256, 0, stream>>>(wbf, X0, Bt1h, Bt1l, bias1, X1, X1b, N);

    // ---- layer 2: X0 = relu([agg(X1)|X1] @ W2) ----
    edge_agg_kernel<<<agrid, 256, 0, stream>>>(X1b, rstart, src_s, et_s, norm_s, att2, wbf, N);
    gemm640_kernel<<<ggrid, 256, 0, stream>>>(wbf, X1, Bt2h, Bt2l, bias2, X0, X0b, N);

    // ---- relation context ----
    relctx_kernel<<<NR, 512, 0, stream>>>(DAD, rel_tab, Wrel, Rc, NR);

    // ---- gated output ----
    output_kernel<<<dim3((S + 1) / 2, 3), 256, 0, stream>>>(
        samples, gate_e, gate_r, ent_emb, rel_emb, X0, Rc, (float*)d_out, S);
}

// Round 9
// 347.904 us; speedup vs baseline: 1.1253x; 1.1253x over previous
//
#include <hip/hip_runtime.h>
#include <hip/hip_bf16.h>

typedef short s8v  __attribute__((ext_vector_type(8)));
typedef float f4v  __attribute__((ext_vector_type(4)));
typedef float f16v __attribute__((ext_vector_type(16)));
typedef unsigned short us8 __attribute__((ext_vector_type(8)));

__device__ __forceinline__ unsigned short f2bf(float x) {   // RTN-even
    unsigned u = __float_as_uint(x);
    unsigned r = ((u >> 16) & 1u) + 0x7FFFu;
    return (unsigned short)((u + r) >> 16);
}
__device__ __forceinline__ float bf2f(unsigned short h) {
    return __uint_as_float(((unsigned)h) << 16);
}

// ---------------- X0 = ent_tab[entity] ----------------
__global__ __launch_bounds__(256) void x0_kernel(
    const float* __restrict__ tab, const int* __restrict__ entity,
    float* __restrict__ X0, int N)
{
    int idx = blockIdx.x * 256 + threadIdx.x;
    int n = idx >> 5, l = idx & 31;
    if (n < N) {
        int src = entity[n];
        *(float4*)&X0[(size_t)n * 128 + l * 4] =
            *(const float4*)&tab[(size_t)src * 128 + l * 4];
    }
}

// ---------------- B prep: Bt[n][k] hi/lo bf16 for both layers ----------------
__global__ __launch_bounds__(256) void bprep_kernel(
    const float* __restrict__ basis1, const float* __restrict__ root1,
    const float* __restrict__ basis2, const float* __restrict__ root2,
    unsigned short* __restrict__ Bt1h, unsigned short* __restrict__ Bt1l,
    unsigned short* __restrict__ Bt2h, unsigned short* __restrict__ Bt2l)
{
    int idx = blockIdx.x * 256 + threadIdx.x;    // 0..81919
    int layer = blockIdx.y;
    int n = idx & 127, k = idx >> 7;             // k 0..639
    const float* basis = layer ? basis2 : basis1;
    const float* root  = layer ? root2  : root1;
    float v = (k < 512) ? basis[((k & 3) << 14) + ((k >> 2) << 7) + n]
                        : root[((k - 512) << 7) + n];
    unsigned short h = f2bf(v);
    unsigned short l = f2bf(v - bf2f(h));
    unsigned short* Bh = layer ? Bt2h : Bt1h;
    unsigned short* Bl = layer ? Bt2l : Bt1l;
    Bh[(size_t)n * 640 + k] = h;
    Bl[(size_t)n * 640 + k] = l;
}

// ---------------- CSR build ----------------
__global__ __launch_bounds__(256) void hist_kernel(
    const int* __restrict__ edge_index, int* __restrict__ deg, int E)
{
    int e = blockIdx.x * 256 + threadIdx.x;
    if (e < E) atomicAdd(&deg[edge_index[E + e]], 1);
}

__global__ __launch_bounds__(1024) void scanA_kernel(
    const int* __restrict__ deg, int* __restrict__ row_start,
    int* __restrict__ btot, int N)
{
    __shared__ int wtot[16];
    __shared__ int woff[16];
    const int tid = threadIdx.x, lane = tid & 63, wid = tid >> 6;
    int i = blockIdx.x * 1024 + tid;
    int v = (i < N) ? deg[i] : 0;
    int x = v;
    #pragma unroll
    for (int d = 1; d < 64; d <<= 1) {
        int t = __shfl_up(x, d, 64);
        if (lane >= d) x += t;
    }
    if (lane == 63) wtot[wid] = x;
    __syncthreads();
    if (wid == 0 && lane < 16) {
        int s = wtot[lane];
        int y = s;
        #pragma unroll
        for (int d = 1; d < 16; d <<= 1) {
            int t = __shfl_up(y, d, 16);
            if (lane >= d) y += t;
        }
        woff[lane] = y - s;
        if (lane == 15) btot[blockIdx.x] = y;
    }
    __syncthreads();
    if (i < N) row_start[i] = woff[wid] + (x - v);
}

__global__ __launch_bounds__(64) void scanB_kernel(
    const int* __restrict__ btot, int* __restrict__ boff,
    int* __restrict__ row_start, int nB, int N)
{
    int t = threadIdx.x;
    int v = (t < nB) ? btot[t] : 0;
    int x = v;
    #pragma unroll
    for (int d = 1; d < 64; d <<= 1) {
        int u = __shfl_up(x, d, 64);
        if (t >= d) x += u;
    }
    if (t < nB) boff[t] = x - v;
    if (t == nB - 1) row_start[N] = x;
}

__global__ __launch_bounds__(1024) void scanC_kernel(
    int* __restrict__ row_start, int* __restrict__ cursor,
    const int* __restrict__ boff, int N)
{
    int i = blockIdx.x * 1024 + threadIdx.x;
    if (i < N) {
        int r = row_start[i] + boff[blockIdx.x];
        row_start[i] = r;
        cursor[i]    = r;
    }
}

__global__ __launch_bounds__(256) void fill_kernel(
    const int* __restrict__ edge_index, const int* __restrict__ edge_type,
    const float* __restrict__ edge_norm, int* __restrict__ cursor,
    int* __restrict__ src_s, int* __restrict__ et_s, float* __restrict__ norm_s, int E)
{
    int e = blockIdx.x * 256 + threadIdx.x;
    if (e >= E) return;
    int dst = edge_index[E + e];
    int pos = atomicAdd(&cursor[dst], 1);
    src_s[pos]  = edge_index[e];
    et_s[pos]   = edge_type[e];
    norm_s[pos] = edge_norm[e];
}

// ---------------- edge agg (fp32 gather) -> w bf16 [N,512], k = 4d+b ----------------
__global__ __launch_bounds__(256) void edge_agg_kernel(
    const float* __restrict__ X,
    const int* __restrict__ row_start,
    const int* __restrict__ src_s, const int* __restrict__ et_s,
    const float* __restrict__ norm_s,
    const float* __restrict__ att,      // [R,4]
    unsigned short* __restrict__ w, int N)
{
    int n = blockIdx.x * 8 + (threadIdx.x >> 5);
    if (n >= N) return;
    int l = threadIdx.x & 31;           // dims 4l..4l+3
    int s0 = row_start[n], s1 = row_start[n + 1];
    float acc[4][4];
    #pragma unroll
    for (int d = 0; d < 4; ++d)
        #pragma unroll
        for (int b = 0; b < 4; ++b) acc[d][b] = 0.f;
    for (int p = s0; p < s1; ++p) {
        int   src  = src_s[p];
        int   et   = et_s[p];
        float norm = norm_s[p];
        float4 a = *(const float4*)(att + (size_t)et * 4);
        a.x *= norm; a.y *= norm; a.z *= norm; a.w *= norm;
        float4 x = *(const float4*)&X[(size_t)src * 128 + (l << 2)];
        float xs[4] = {x.x, x.y, x.z, x.w};
        #pragma unroll
        for (int d = 0; d < 4; ++d) {
            acc[d][0] = fmaf(a.x, xs[d], acc[d][0]);
            acc[d][1] = fmaf(a.y, xs[d], acc[d][1]);
            acc[d][2] = fmaf(a.z, xs[d], acc[d][2]);
            acc[d][3] = fmaf(a.w, xs[d], acc[d][3]);
        }
    }
    float inv = 1.0f / fmaxf((float)(s1 - s0), 1.0f);
    #pragma unroll
    for (int d = 0; d < 4; ++d) {
        ushort4 h;
        h.x = f2bf(acc[d][0] * inv);
        h.y = f2bf(acc[d][1] * inv);
        h.z = f2bf(acc[d][2] * inv);
        h.w = f2bf(acc[d][3] * inv);
        *(ushort4*)&w[(size_t)n * 512 + (l << 4) + (d << 2)] = h;
    }
}

// ---------------- GEMM K=640, split-bf16 via 32x32x16 MFMA ----------------
// 64 rows x 128 cols per block, 4 waves: wave = (row-half 32, col-half 64 = 2 tiles).
// A = [w(bf16, k<512) | X(fp32 split, k>=512)], B = Bt^T pre-split hi/lo.
// Register prefetch: next chunk's A/B loads stay in flight across the MFMA section.
__global__ __launch_bounds__(256) void gemm640_kernel(
    const unsigned short* __restrict__ wbf,   // [N,512] bf16
    const float* __restrict__ X,              // [N,128] fp32
    const unsigned short* __restrict__ Bth,   // [128][640]
    const unsigned short* __restrict__ Btl,
    const float* __restrict__ bias,
    float* __restrict__ Xout, int N)
{
    __shared__ unsigned short A_hi[64 * 40];
    __shared__ unsigned short A_lo[64 * 40];
    __shared__ unsigned short B_hi[128 * 40];
    __shared__ unsigned short B_lo[128 * 40];

    const int tid  = threadIdx.x;
    const int row0 = blockIdx.x * 64;
    const int lane = tid & 63, wv = tid >> 6;
    const int m    = lane & 31;            // row/col within a 32-tile
    const int kh   = (lane >> 5) << 3;     // k-half offset within k16 (0/8)
    const int rt   = (wv & 1) << 5;        // row tile base 0/32
    const int c0w  = (wv >> 1) << 6;       // col base 0/64

    // staging indices
    const int awr = tid >> 2, awk = (tid & 3) << 3;           // A w-chunk (1 us8)
    const int bn0 = tid >> 2,          bk0 = (tid & 3) << 3;  // B (2 us8 per array)
    const int bn1 = (tid + 256) >> 2,  bk1 = ((tid + 256) & 3) << 3;

    const us8 z8 = {0,0,0,0,0,0,0,0};
    us8 pA = z8, pBh0, pBh1, pBl0, pBl1;

    auto loadAw = [&](int k0) {
        int gr = row0 + awr;
        pA = (gr < N) ? *(const us8*)&wbf[(size_t)gr * 512 + k0 + awk] : z8;
    };
    auto loadB = [&](int k0) {
        pBh0 = *(const us8*)&Bth[(size_t)bn0 * 640 + k0 + bk0];
        pBh1 = *(const us8*)&Bth[(size_t)bn1 * 640 + k0 + bk1];
        pBl0 = *(const us8*)&Btl[(size_t)bn0 * 640 + k0 + bk0];
        pBl1 = *(const us8*)&Btl[(size_t)bn1 * 640 + k0 + bk1];
    };

    f16v acc0, acc1;
    #pragma unroll
    for (int i = 0; i < 16; ++i) { acc0[i] = 0.f; acc1[i] = 0.f; }

    loadAw(0); loadB(0);

    for (int kc = 0; kc < 20; ++kc) {
        const int k0 = kc * 32;
        if (kc) __syncthreads();           // prev chunk's LDS fully consumed

        if (k0 < 512) {
            *(us8*)&A_hi[awr * 40 + awk] = pA;
        } else {
            // direct staging of X chunk (4 of 20 chunks): fp32 -> hi/lo bf16
            #pragma unroll
            for (int i = 0; i < 2; ++i) {
                int idx = tid + i * 256;
                int r = idx >> 3, kv = (idx & 7) << 2;
                int gr = row0 + r;
                float4 v = make_float4(0.f, 0.f, 0.f, 0.f);
                if (gr < N) v = *(const float4*)&X[(size_t)gr * 128 + (k0 - 512) + kv];
                ushort4 h, l;
                h.x = f2bf(v.x); l.x = f2bf(v.x - bf2f(h.x));
                h.y = f2bf(v.y); l.y = f2bf(v.y - bf2f(h.y));
                h.z = f2bf(v.z); l.z = f2bf(v.z - bf2f(h.z));
                h.w = f2bf(v.w); l.w = f2bf(v.w - bf2f(h.w));
                *(ushort4*)&A_hi[r * 40 + kv] = h;
                *(ushort4*)&A_lo[r * 40 + kv] = l;
            }
        }
        *(us8*)&B_hi[bn0 * 40 + bk0] = pBh0;
        *(us8*)&B_hi[bn1 * 40 + bk1] = pBh1;
        *(us8*)&B_lo[bn0 * 40 + bk0] = pBl0;
        *(us8*)&B_lo[bn1 * 40 + bk1] = pBl1;
        __syncthreads();

        if (kc < 19) {                     // prefetch next chunk into registers
            if (k0 + 32 < 512) loadAw(k0 + 32);
            loadB(k0 + 32);
        }

        #pragma unroll
        for (int h = 0; h < 2; ++h) {      // two k16 steps per 32-k chunk
            const int off = h * 16 + kh;
            s8v aH = *(const s8v*)&A_hi[(rt + m) * 40 + off];
            if (k0 < 512) {
                {
                    const int nb = (c0w + m) * 40 + off;
                    s8v bH = *(const s8v*)&B_hi[nb];
                    s8v bL = *(const s8v*)&B_lo[nb];
                    acc0 = __builtin_amdgcn_mfma_f32_32x32x16_bf16(aH, bL, acc0, 0, 0, 0);
                    acc0 = __builtin_amdgcn_mfma_f32_32x32x16_bf16(aH, bH, acc0, 0, 0, 0);
                }
                {
                    const int nb = (c0w + 32 + m) * 40 + off;
                    s8v bH = *(const s8v*)&B_hi[nb];
                    s8v bL = *(const s8v*)&B_lo[nb];
                    acc1 = __builtin_amdgcn_mfma_f32_32x32x16_bf16(aH, bL, acc1, 0, 0, 0);
                    acc1 = __builtin_amdgcn_mfma_f32_32x32x16_bf16(aH, bH, acc1, 0, 0, 0);
                }
            } else {
                s8v aL = *(const s8v*)&A_lo[(rt + m) * 40 + off];
                {
                    const int nb = (c0w + m) * 40 + off;
                    s8v bH = *(const s8v*)&B_hi[nb];
                    s8v bL = *(const s8v*)&B_lo[nb];
                    acc0 = __builtin_amdgcn_mfma_f32_32x32x16_bf16(aL, bH, acc0, 0, 0, 0);
                    acc0 = __builtin_amdgcn_mfma_f32_32x32x16_bf16(aH, bL, acc0, 0, 0, 0);
                    acc0 = __builtin_amdgcn_mfma_f32_32x32x16_bf16(aH, bH, acc0, 0, 0, 0);
                }
                {
                    const int nb = (c0w + 32 + m) * 40 + off;
                    s8v bH = *(const s8v*)&B_hi[nb];
                    s8v bL = *(const s8v*)&B_lo[nb];
                    acc1 = __builtin_amdgcn_mfma_f32_32x32x16_bf16(aL, bH, acc1, 0, 0, 0);
                    acc1 = __builtin_amdgcn_mfma_f32_32x32x16_bf16(aH, bL, acc1, 0, 0, 0);
                    acc1 = __builtin_amdgcn_mfma_f32_32x32x16_bf16(aH, bH, acc1, 0, 0, 0);
                }
            }
        }
    }

    // epilogue: 32x32 C/D layout: col = lane&31, row = (reg&3) + 8*(reg>>2) + 4*(lane>>5)
    const int rbase = rt + ((lane >> 5) << 2);
    #pragma unroll
    for (int ct = 0; ct < 2; ++ct) {
        int gc = c0w + ct * 32 + m;
        float bv = bias[gc];
        #pragma unroll
        for (int reg = 0; reg < 16; ++reg) {
            int gr = row0 + rbase + (reg & 3) + ((reg >> 2) << 3);
            if (gr < N) {
                float v = ct ? acc1[reg] : acc0[reg];
                Xout[(size_t)gr * 128 + gc] = fmaxf(v + bv, 0.f);
            }
        }
    }
}

// ---------------- relation context: R2 = relu(DAD @ tab @ W) ----------------
__global__ __launch_bounds__(512) void relctx_kernel(
    const float* __restrict__ DAD,
    const float* __restrict__ tab,
    const float* __restrict__ W,
    float* __restrict__ R2, int NR)
{
    __shared__ float part[4][128];
    __shared__ float r1s[128];
    int r = blockIdx.x;
    int t = threadIdx.x;
    int o = t & 127, q = t >> 7;
    float s = 0.f;
    #pragma unroll 4
    for (int j = q; j < NR; j += 4)
        s = fmaf(DAD[r * NR + j], tab[j * 128 + o], s);
    part[q][o] = s;
    __syncthreads();
    if (t < 128) r1s[t] = part[0][t] + part[1][t] + part[2][t] + part[3][t];
    __syncthreads();
    float s2 = 0.f;
    #pragma unroll 8
    for (int k = q * 32; k < q * 32 + 32; ++k)
        s2 = fmaf(r1s[k], W[k * 128 + o], s2);
    part[q][o] = s2;
    __syncthreads();
    if (t < 128)
        R2[r * 128 + t] = fmaxf(part[0][t] + part[1][t] + part[2][t] + part[3][t], 0.f);
}

// ---------------- gated output ----------------
__global__ __launch_bounds__(256) void output_kernel(
    const int* __restrict__ samples,
    const float* __restrict__ gate_e,
    const float* __restrict__ gate_r,
    const float* __restrict__ ent_emb,
    const float* __restrict__ rel_emb,
    const float* __restrict__ ctx2,
    const float* __restrict__ relctx,
    float* __restrict__ out, int S)
{
    int s = blockIdx.x * 2 + (threadIdx.x >> 7);
    if (s >= S) return;
    int p = blockIdx.y;
    int o = threadIdx.x & 127;
    float v;
    if (p == 1) {
        int idx = samples[s * 3 + 1];
        float g = 1.0f / (1.0f + __expf(-gate_r[o]));
        v = g * rel_emb[idx * 128 + o] + (1.0f - g) * relctx[idx * 128 + o];
    } else {
        int idx = samples[s * 3 + (p == 0 ? 0 : 2)];
        float g = 1.0f / (1.0f + __expf(-gate_e[o]));
        v = g * ent_emb[(size_t)idx * 128 + o] + (1.0f - g) * ctx2[(size_t)idx * 128 + o];
    }
    out[(size_t)p * S * 128 + (size_t)s * 128 + o] = v;
}

extern "C" void kernel_launch(void* const* d_in, const int* in_sizes, int n_in,
                              void* d_out, int out_size, void* d_ws, size_t ws_size,
                              hipStream_t stream)
{
    const int*   entity     = (const int*)d_in[0];
    const int*   edge_index = (const int*)d_in[1];
    const int*   edge_type  = (const int*)d_in[2];
    const float* edge_norm  = (const float*)d_in[3];
    const int*   samples    = (const int*)d_in[4];
    const float* DAD        = (const float*)d_in[5];
    const float* ent_emb    = (const float*)d_in[6];
    const float* rel_emb    = (const float*)d_in[7];
    const float* ent_tab    = (const float*)d_in[8];
    const float* rel_tab    = (const float*)d_in[9];
    const float* Wrel       = (const float*)d_in[10];
    const float* gate_e     = (const float*)d_in[11];
    const float* gate_r     = (const float*)d_in[12];
    const float* basis1     = (const float*)d_in[13];
    const float* att1       = (const float*)d_in[14];
    const float* root1      = (const float*)d_in[15];
    const float* bias1      = (const float*)d_in[16];
    const float* basis2     = (const float*)d_in[17];
    const float* att2       = (const float*)d_in[18];
    const float* root2      = (const float*)d_in[19];
    const float* bias2      = (const float*)d_in[20];

    const int N  = in_sizes[0];        // 50000
    const int E  = in_sizes[2];        // 200000
    const int S  = in_sizes[4] / 3;    // 20000
    const int NR = in_sizes[9] / 128;  // 200

    float* ws      = (float*)d_ws;
    float* X0      = ws;                               // [N,128] f32
    float* X1      = X0 + (size_t)N * 128;             // [N,128] f32
    unsigned short* wbf = (unsigned short*)(X1 + (size_t)N * 128); // [N,512] bf16
    float* Rc      = (float*)(wbf + (size_t)N * 512);  // [NR,128] f32
    int*   deg     = (int*)(Rc + (size_t)NR * 128);    // [N]
    int*   rstart  = deg + N;                          // [N+1]
    int*   cursor  = rstart + N + 1;                   // [N]
    int*   src_s   = cursor + N;                       // [E]
    int*   et_s    = src_s + E;                        // [E]
    float* norm_s  = (float*)(et_s + E);               // [E]
    int*   btot    = (int*)(norm_s + E);               // [64]
    int*   boff    = btot + 64;                        // [64]
    uintptr_t bt   = ((uintptr_t)(boff + 64) + 15) & ~(uintptr_t)15;
    unsigned short* Bt1h = (unsigned short*)bt;        // [128*640] each
    unsigned short* Bt1l = Bt1h + 128 * 640;
    unsigned short* Bt2h = Bt1l + 128 * 640;
    unsigned short* Bt2l = Bt2h + 128 * 640;

    const int egrid = (E + 255) / 256;
    const int ggrid = (N + 63) / 64;
    const int agrid = (N + 7) / 8;
    const int nB    = (N + 1023) / 1024;

    // ---- weight prep + CSR build ----
    bprep_kernel<<<dim3(320, 2), 256, 0, stream>>>(basis1, root1, basis2, root2,
                                                   Bt1h, Bt1l, Bt2h, Bt2l);
    hipMemsetAsync(deg, 0, (size_t)N * sizeof(int), stream);
    hist_kernel<<<egrid, 256, 0, stream>>>(edge_index, deg, E);
    scanA_kernel<<<nB, 1024, 0, stream>>>(deg, rstart, btot, N);
    scanB_kernel<<<1, 64, 0, stream>>>(btot, boff, rstart, nB, N);
    scanC_kernel<<<nB, 1024, 0, stream>>>(rstart, cursor, boff, N);
    fill_kernel<<<egrid, 256, 0, stream>>>(edge_index, edge_type, edge_norm, cursor,
                                           src_s, et_s, norm_s, E);

    // ---- X0 = ent_tab[entity] ----
    x0_kernel<<<(N * 32 + 255) / 256, 256, 0, stream>>>(ent_tab, entity, X0, N);

    // ---- layer 1: X1 = relu([agg(X0)|X0] @ W1) ----
    edge_agg_kernel<<<agrid, 256, 0, stream>>>(X0, rstart, src_s, et_s, norm_s, att1, wbf, N);
    gemm640_kernel<<<ggrid, 256, 0, stream>>>(wbf, X0, Bt1h, Bt1l, bias1, X1, N);

    // ---- layer 2: X0 = relu([agg(X1)|X1] @ W2) ----
    edge_agg_kernel<<<agrid, 256, 0, stream>>>(X1, rstart, src_s, et_s, norm_s, att2, wbf, N);
    gemm640_kernel<<<ggrid, 256, 0, stream>>>(wbf, X1, Bt2h, Bt2l, bias2, X0, N);

    // ---- relation context ----
    relctx_kernel<<<NR, 512, 0, stream>>>(DAD, rel_tab, Wrel, Rc, NR);

    // ---- gated output ----
    output_kernel<<<dim3((S + 1) / 2, 3), 256, 0, stream>>>(
        samples, gate_e, gate_r, ent_emb, rel_emb, X0, Rc, (float*)d_out, S);
}